// Round 7
// baseline (565.574 us; speedup 1.0000x reference)
//
#include <hip/hip_runtime.h>
#include <hip/hip_cooperative_groups.h>
#include <math.h>

namespace cg = cooperative_groups;

#define N_NODES 8192
#define N3      24576              // N_NODES * 3
#define LR_C 0.01f
#define EPS_C 1e-6f
#define HASH_SLOTS (1u << 20)      // 4 MiB
#define HEMPTY 0xFFFFFFFFu
#define NBLK 256
#define NTHR 512

struct Params {
    const float* pos;
    const int*   edge_index;
    const int*   dist_idx;
    const float* dist_target;
    const float* min_dist;
    float*       out;        // x (24576) then curvature (8192)
    float*       x1;
    float4*      z4;         // (dv*x, dv*y, dv*z, dv)
    unsigned char* flags;
    float*       corr_part;  // 64*24576 f32; overlaid by rep_part 32*8192 f4
    unsigned int* hash;      // 4 MiB; overlaid (with deg) by lap_part
    int*         deg_part;   // 64*8192
    float*       lap_part;   // 64*24576 (== hash base)
    int E, K;
};

__global__ __launch_bounds__(NTHR, 2) void mega(Params p) {
    __shared__ __align__(16) float smf[N3];      // 96 KiB, phase-aliased
    cg::grid_group grid = cg::this_grid();
    const int bid = blockIdx.x;
    const int tid = threadIdx.x;

    // ---------------- P0: clear hash (4 MiB) ----------------
    {
        uint4* h4 = (uint4*)p.hash;
        int idx = bid * NTHR + tid;              // 131072 threads, 2 uint4 each
        h4[idx]          = make_uint4(HEMPTY, HEMPTY, HEMPTY, HEMPTY);
        h4[idx + 131072] = make_uint4(HEMPTY, HEMPTY, HEMPTY, HEMPTY);
    }
    __threadfence();
    grid.sync();

    // ---------------- P1: corr hist (0-63)  ||  hash flags (64-255) --------
    if (bid < 64) {
        for (int t = tid; t < N3; t += NTHR) smf[t] = 0.f;
        __syncthreads();
        int per = (p.K + 63) / 64;                         // 1024
        int base = bid * per;
        for (int kk = tid; kk < per; kk += NTHR) {
            int k = base + kk;
            if (k >= p.K) break;
            int i = p.dist_idx[2 * k], j = p.dist_idx[2 * k + 1];
            float ax = p.pos[3 * i], ay = p.pos[3 * i + 1], az = p.pos[3 * i + 2];
            float bx = p.pos[3 * j], by = p.pos[3 * j + 1], bz = p.pos[3 * j + 2];
            float vx = ax - bx, vy = ay - by, vz = az - bz;
            float dist = sqrtf(vx * vx + vy * vy + vz * vz + 1e-12f);
            bool valid = (dist > EPS_C) && (i != j);
            float coef = valid ? (LR_C * 0.5f) * (dist - p.dist_target[k]) / dist
                               : 0.0f;
            if (coef != 0.0f) {
                float cx = coef * vx, cy = coef * vy, cz = coef * vz;
                atomicAdd(&smf[3 * i],     -cx);
                atomicAdd(&smf[3 * i + 1], -cy);
                atomicAdd(&smf[3 * i + 2], -cz);
                atomicAdd(&smf[3 * j],      cx);
                atomicAdd(&smf[3 * j + 1],  cy);
                atomicAdd(&smf[3 * j + 2],  cz);
            }
        }
        __syncthreads();
        float* dst = p.corr_part + (size_t)bid * N3;
        for (int t = tid; t < N3; t += NTHR) dst[t] = smf[t];
    } else {
        for (int k = (bid - 64) * NTHR + tid; k < p.E; k += 192 * NTHR) {
            int a = p.edge_index[k];
            int b = p.edge_index[p.E + k];
            a = min(max(a, 0), N_NODES - 1);
            b = min(max(b, 0), N_NODES - 1);
            unsigned int key = ((unsigned)a << 13) | (unsigned)b;  // 26 bits
            unsigned int h = (key * 2654435761u) >> 12;            // [0, 2^20)
            bool unique = false;
            while (true) {
                unsigned int old = atomicCAS(&p.hash[h], HEMPTY, key);
                if (old == HEMPTY) { unique = true; break; }
                if (old == key)    { break; }
                h = (h + 1) & (HASH_SLOTS - 1);
            }
            p.flags[k] = unique ? 1 : 0;
        }
    }
    __threadfence();
    grid.sync();

    // ---------------- P2: x1 reduce (0-63)  ||  deg hist (64-127) ----------
    if (bid < 64) {
        int e = bid * 384 + tid;                 // 64*384 = 24576
        if (tid < 384) {
            float s = p.pos[e];
            #pragma unroll 8
            for (int q = 0; q < 64; ++q) s += p.corr_part[(size_t)q * N3 + e];
            p.x1[e] = s;
        }
    } else if (bid < 128) {
        int* hist = (int*)smf;                   // 32 KiB of the union
        for (int t = tid; t < N_NODES; t += NTHR) hist[t] = 0;
        __syncthreads();
        int b = bid - 64;
        int per = (p.E + 63) / 64;               // 4096
        int base = b * per;
        for (int kk = tid; kk < per; kk += NTHR) {
            int k = base + kk;
            if (k >= p.E) break;
            if (!p.flags[k]) continue;
            int a = p.edge_index[k];
            int c = p.edge_index[p.E + k];
            a = min(max(a, 0), N_NODES - 1);
            c = min(max(c, 0), N_NODES - 1);
            atomicAdd(&hist[a], 1);
            atomicAdd(&hist[c], 1);
        }
        __syncthreads();
        int* dst = p.deg_part + (size_t)b * N_NODES;
        for (int t = tid; t < N_NODES; t += NTHR) dst[t] = hist[t];
    }
    __threadfence();
    grid.sync();

    // ---------------- P3: repulsion, all blocks, 2 i-rows/thread -----------
    {
        float4* pj = (float4*)smf;               // 4 KiB j-tile
        int ic = bid >> 5;                       // 0..7   (1024 i's)
        int jc = bid & 31;                       // 0..31  (256 j's)
        int jbase = jc << 8;
        if (tid < 256) {
            int j = jbase + tid;
            float a = p.x1[3 * j], b = p.x1[3 * j + 1], c = p.x1[3 * j + 2];
            pj[tid] = make_float4(a, b, c, a * a + b * b + c * c);
        }
        __syncthreads();
        int i0 = (ic << 10) + tid;
        int i1 = i0 + 512;
        float x0v = p.x1[3 * i0], y0v = p.x1[3 * i0 + 1], z0v = p.x1[3 * i0 + 2];
        float x1v = p.x1[3 * i1], y1v = p.x1[3 * i1 + 1], z1v = p.x1[3 * i1 + 2];
        float sq0 = x0v * x0v + y0v * y0v + z0v * z0v;
        float sq1 = x1v * x1v + y1v * y1v + z1v * z1v;
        float md = p.min_dist[0];
        const float c0 = 0.5f * LR_C;            // 0.005
        float c1 = c0 * md;
        int di0 = i0 - jbase, di1 = i1 - jbase;  // self-pair slots (may be OOR)
        float S0 = 0.f, ax0 = 0.f, ay0 = 0.f, az0 = 0.f;
        float S1 = 0.f, ax1 = 0.f, ay1 = 0.f, az1 = 0.f;
        #pragma unroll 4
        for (int jj = 0; jj < 256; ++jj) {
            float4 q = pj[jj];
            float dot0 = fmaf(x0v, q.x, fmaf(y0v, q.y, z0v * q.z));
            float d20 = fmaf(-2.0f, dot0, sq0 + q.w);
            float r0 = __builtin_amdgcn_rsqf(fmaxf(d20, 1e-12f));
            float w0 = fmaxf(fmaf(c1, r0, -c0), 0.0f);     // >0 iff d < md
            w0 = (d20 > 1e-12f && jj != di0) ? w0 : 0.0f;
            S0 += w0;
            ax0 = fmaf(w0, q.x, ax0); ay0 = fmaf(w0, q.y, ay0); az0 = fmaf(w0, q.z, az0);
            float dot1 = fmaf(x1v, q.x, fmaf(y1v, q.y, z1v * q.z));
            float d21 = fmaf(-2.0f, dot1, sq1 + q.w);
            float r1 = __builtin_amdgcn_rsqf(fmaxf(d21, 1e-12f));
            float w1 = fmaxf(fmaf(c1, r1, -c0), 0.0f);
            w1 = (d21 > 1e-12f && jj != di1) ? w1 : 0.0f;
            S1 += w1;
            ax1 = fmaf(w1, q.x, ax1); ay1 = fmaf(w1, q.y, ay1); az1 = fmaf(w1, q.z, az1);
        }
        float4* rep = (float4*)p.corr_part;      // overlay (corr_part dead)
        rep[(size_t)jc * N_NODES + i0] = make_float4(ax0, ay0, az0, S0);
        rep[(size_t)jc * N_NODES + i1] = make_float4(ax1, ay1, az1, S1);
    }
    __threadfence();
    grid.sync();

    // ---------------- P4: finalize x2/out/z4 (blocks 0-15) -----------------
    if (bid < 16) {
        int row = bid * NTHR + tid;              // 8192 rows
        const float4* rep = (const float4*)p.corr_part;
        float S = 0.f, ax = 0.f, ay = 0.f, az = 0.f;
        #pragma unroll 8
        for (int c = 0; c < 32; ++c) {
            float4 q = rep[(size_t)c * N_NODES + row];
            ax += q.x; ay += q.y; az += q.z; S += q.w;
        }
        int d = 0;
        #pragma unroll 8
        for (int q = 0; q < 64; ++q) d += p.deg_part[(size_t)q * N_NODES + row];
        float xi = p.x1[3 * row], yi = p.x1[3 * row + 1], zi = p.x1[3 * row + 2];
        float ox = xi + xi * S - ax;
        float oy = yi + yi * S - ay;
        float oz = zi + zi * S - az;
        p.out[3 * row] = ox; p.out[3 * row + 1] = oy; p.out[3 * row + 2] = oz;
        float dv = (d == 0) ? 0.0f : 1.0f / sqrtf((float)d + EPS_C);
        p.z4[row] = make_float4(dv * ox, dv * oy, dv * oz, dv);
    }
    __threadfence();
    grid.sync();

    // ---------------- P5: lap LDS histogram (blocks 0-63) ------------------
    if (bid < 64) {
        for (int t = tid; t < N3; t += NTHR) smf[t] = 0.f;
        __syncthreads();
        int per = (p.E + 63) / 64;               // 4096
        int base = bid * per;
        for (int kk = tid; kk < per; kk += NTHR) {
            int k = base + kk;
            if (k >= p.E) break;
            if (!p.flags[k]) continue;
            int a = p.edge_index[k];
            int c = p.edge_index[p.E + k];
            a = min(max(a, 0), N_NODES - 1);
            c = min(max(c, 0), N_NODES - 1);
            float4 zc = p.z4[c];
            float4 za = p.z4[a];
            atomicAdd(&smf[3 * a],     zc.x);
            atomicAdd(&smf[3 * a + 1], zc.y);
            atomicAdd(&smf[3 * a + 2], zc.z);
            atomicAdd(&smf[3 * c],     za.x);
            atomicAdd(&smf[3 * c + 1], za.y);
            atomicAdd(&smf[3 * c + 2], za.z);
        }
        __syncthreads();
        float* dst = p.lap_part + (size_t)bid * N3;
        for (int t = tid; t < N3; t += NTHR) dst[t] = smf[t];
    }
    __threadfence();
    grid.sync();

    // ---------------- P6: curvature (blocks 0-15) --------------------------
    if (bid < 16) {
        int row = bid * NTHR + tid;
        float lx = 0.f, ly = 0.f, lz = 0.f;
        #pragma unroll 8
        for (int q = 0; q < 64; ++q) {
            const float* src = p.lap_part + (size_t)q * N3 + 3 * row;
            lx += src[0]; ly += src[1]; lz += src[2];
        }
        float dv = p.z4[row].w;
        float Lx = p.out[3 * row]     - dv * lx;
        float Ly = p.out[3 * row + 1] - dv * ly;
        float Lz = p.out[3 * row + 2] - dv * lz;
        p.out[N3 + row] = sqrtf(Lx * Lx + Ly * Ly + Lz * Lz + 1e-12f);
    }
}

extern "C" void kernel_launch(void* const* d_in, const int* in_sizes, int n_in,
                              void* d_out, int out_size, void* d_ws, size_t ws_size,
                              hipStream_t stream) {
    Params prm;
    prm.pos         = (const float*)d_in[0];
    prm.edge_index  = (const int*)d_in[1];
    prm.dist_idx    = (const int*)d_in[2];
    prm.dist_target = (const float*)d_in[3];
    prm.min_dist    = (const float*)d_in[4];
    prm.out         = (float*)d_out;
    prm.E = in_sizes[1] / 2;   // 262144
    prm.K = in_sizes[2] / 2;   // 65536

    // ---- workspace layout (16B aligned), lifetime overlays ----
    char* ws = (char*)d_ws;
    const size_t X1_OFF   = 0;                                   //  96 KiB
    const size_t Z4_OFF   = X1_OFF + (size_t)N3 * 4;             // 128 KiB
    const size_t FLAG_OFF = Z4_OFF + (size_t)N_NODES * 16;       // 256 KiB
    const size_t R1_OFF   = FLAG_OFF + (size_t)prm.E;            // 6 MiB: corr/rep
    const size_t R2_OFF   = R1_OFF + (size_t)64 * N3 * 4;        // 6 MiB: hash+deg / lap

    prm.x1        = (float*)(ws + X1_OFF);
    prm.z4        = (float4*)(ws + Z4_OFF);
    prm.flags     = (unsigned char*)(ws + FLAG_OFF);
    prm.corr_part = (float*)(ws + R1_OFF);
    prm.hash      = (unsigned int*)(ws + R2_OFF);
    prm.deg_part  = (int*)(ws + R2_OFF + (size_t)HASH_SLOTS * 4);
    prm.lap_part  = (float*)(ws + R2_OFF);                       // overlay

    void* args[] = { &prm };
    hipLaunchCooperativeKernel((const void*)mega, dim3(NBLK), dim3(NTHR),
                               args, 0, stream);
}

// Round 8
// 114.849 us; speedup vs baseline: 4.9245x; 4.9245x over previous
//
#include <hip/hip_runtime.h>
#include <math.h>

#define N_NODES 8192
#define N3      24576              // N_NODES * 3
#define LR_C 0.01f
#define EPS_C 1e-6f
#define HASH_SLOTS (1u << 20)      // 4 MiB
#define HEMPTY 0xFFFFFFFFu
#define NB_SC 64                   // corr-histogram blocks
#define NB_DG 64                   // degree-histogram blocks
#define NB_LP 64                   // laplacian-histogram blocks

// =============== K_A: corr LDS-hist (blk 0-63) || hash clear (blk 64-319) ====
__global__ __launch_bounds__(512) void kA_corr_hashclear(
        const float* __restrict__ x0, const int* __restrict__ dist_idx,
        const float* __restrict__ dist_target,
        float* __restrict__ corr_part, uint4* __restrict__ hash4, int K) {
    __shared__ __align__(16) float smf[N3];          // 96 KiB
    int bid = blockIdx.x, tid = threadIdx.x;
    if (bid < NB_SC) {
        for (int t = tid; t < N3; t += 512) smf[t] = 0.f;
        __syncthreads();
        int per = (K + NB_SC - 1) / NB_SC;           // 1024
        int base = bid * per;
        for (int kk = tid; kk < per; kk += 512) {
            int k = base + kk;
            if (k >= K) break;
            int i = dist_idx[2 * k], j = dist_idx[2 * k + 1];
            float ax = x0[3 * i], ay = x0[3 * i + 1], az = x0[3 * i + 2];
            float bx = x0[3 * j], by = x0[3 * j + 1], bz = x0[3 * j + 2];
            float vx = ax - bx, vy = ay - by, vz = az - bz;
            float dist = sqrtf(vx * vx + vy * vy + vz * vz + 1e-12f);
            bool valid = (dist > EPS_C) && (i != j);
            float coef = valid ? (LR_C * 0.5f) * (dist - dist_target[k]) / dist
                               : 0.0f;
            if (coef != 0.0f) {
                float cx = coef * vx, cy = coef * vy, cz = coef * vz;
                atomicAdd(&smf[3 * i],     -cx);
                atomicAdd(&smf[3 * i + 1], -cy);
                atomicAdd(&smf[3 * i + 2], -cz);
                atomicAdd(&smf[3 * j],      cx);
                atomicAdd(&smf[3 * j + 1],  cy);
                atomicAdd(&smf[3 * j + 2],  cz);
            }
        }
        __syncthreads();
        float* dst = corr_part + (size_t)bid * N3;
        for (int t = tid; t < N3; t += 512) dst[t] = smf[t];
    } else {
        // 256 blocks clear 262144 uint4: 1024 per block, 2 per thread
        int base = (bid - NB_SC) * 1024;
        hash4[base + tid]       = make_uint4(HEMPTY, HEMPTY, HEMPTY, HEMPTY);
        hash4[base + tid + 512] = make_uint4(HEMPTY, HEMPTY, HEMPTY, HEMPTY);
    }
}

// =============== K_B: x1 reduce (blk 0-95) || hash CAS flags (blk 96-1119) ==
__global__ __launch_bounds__(256) void kB_x1_hashflags(
        const float* __restrict__ pos, const float* __restrict__ corr_part,
        float* __restrict__ x1, const int* __restrict__ edge_index,
        unsigned int* __restrict__ hash, unsigned char* __restrict__ flags,
        int E) {
    int bid = blockIdx.x, tid = threadIdx.x;
    if (bid < 96) {
        int e = bid * 256 + tid;                     // 24576 elems
        float s = pos[e];
        #pragma unroll 8
        for (int q = 0; q < NB_SC; ++q) s += corr_part[(size_t)q * N3 + e];
        x1[e] = s;
    } else {
        int k = (bid - 96) * 256 + tid;
        if (k >= E) return;
        int a = edge_index[k];
        int b = edge_index[E + k];
        a = min(max(a, 0), N_NODES - 1);
        b = min(max(b, 0), N_NODES - 1);
        unsigned int key = ((unsigned)a << 13) | (unsigned)b;   // 26 bits
        unsigned int h = (key * 2654435761u) >> 12;             // [0, 2^20)
        bool unique = false;
        while (true) {
            unsigned int old = atomicCAS(&hash[h], HEMPTY, key);
            if (old == HEMPTY) { unique = true; break; }
            if (old == key)    { break; }
            h = (h + 1) & (HASH_SLOTS - 1);
        }
        flags[k] = unique ? 1 : 0;
    }
}

// =============== K_C: repulsion (blk 0-511, 2 rows/thread) || deg (512-575) ==
__global__ __launch_bounds__(256) void kC_rep_deg(
        const float* __restrict__ x1, const float* __restrict__ min_dist,
        float4* __restrict__ rep_part, const int* __restrict__ edge_index,
        const unsigned char* __restrict__ flags, int* __restrict__ deg_part,
        int E) {
    __shared__ __align__(16) unsigned char smu[32768];   // 32 KiB union
    int bid = blockIdx.x, tid = threadIdx.x;
    if (bid < 512) {
        float4* pj = (float4*)smu;                   // 4 KiB j-tile
        int ic = bid >> 5;                           // 0..15 (512 rows each)
        int jc = bid & 31;                           // 0..31 (256 cols each)
        int jbase = jc << 8;
        {
            int j = jbase + tid;
            float a = x1[3 * j], b = x1[3 * j + 1], c = x1[3 * j + 2];
            pj[tid] = make_float4(a, b, c, a * a + b * b + c * c);
        }
        __syncthreads();
        int i0 = (ic << 9) + tid;
        int i1 = i0 + 256;
        float x0v = x1[3 * i0], y0v = x1[3 * i0 + 1], z0v = x1[3 * i0 + 2];
        float x1v = x1[3 * i1], y1v = x1[3 * i1 + 1], z1v = x1[3 * i1 + 2];
        float sq0 = x0v * x0v + y0v * y0v + z0v * z0v;
        float sq1 = x1v * x1v + y1v * y1v + z1v * z1v;
        float md = min_dist[0];
        const float c0 = 0.5f * LR_C;                // 0.005
        float c1 = c0 * md;
        int di0 = i0 - jbase, di1 = i1 - jbase;      // self slots (may be OOR)
        float S0 = 0.f, ax0 = 0.f, ay0 = 0.f, az0 = 0.f;
        float S1 = 0.f, ax1 = 0.f, ay1 = 0.f, az1 = 0.f;
        #pragma unroll 4
        for (int jj = 0; jj < 256; ++jj) {
            float4 q = pj[jj];
            float dot0 = fmaf(x0v, q.x, fmaf(y0v, q.y, z0v * q.z));
            float d20 = fmaf(-2.0f, dot0, sq0 + q.w);
            float r0 = __builtin_amdgcn_rsqf(fmaxf(d20, 1e-12f));
            float w0 = fmaxf(fmaf(c1, r0, -c0), 0.0f);       // >0 iff d < md
            w0 = (d20 > 1e-12f && jj != di0) ? w0 : 0.0f;
            S0 += w0;
            ax0 = fmaf(w0, q.x, ax0); ay0 = fmaf(w0, q.y, ay0); az0 = fmaf(w0, q.z, az0);
            float dot1 = fmaf(x1v, q.x, fmaf(y1v, q.y, z1v * q.z));
            float d21 = fmaf(-2.0f, dot1, sq1 + q.w);
            float r1 = __builtin_amdgcn_rsqf(fmaxf(d21, 1e-12f));
            float w1 = fmaxf(fmaf(c1, r1, -c0), 0.0f);
            w1 = (d21 > 1e-12f && jj != di1) ? w1 : 0.0f;
            S1 += w1;
            ax1 = fmaf(w1, q.x, ax1); ay1 = fmaf(w1, q.y, ay1); az1 = fmaf(w1, q.z, az1);
        }
        rep_part[(size_t)jc * N_NODES + i0] = make_float4(ax0, ay0, az0, S0);
        rep_part[(size_t)jc * N_NODES + i1] = make_float4(ax1, ay1, az1, S1);
    } else {
        int* hist = (int*)smu;                       // 32 KiB histogram
        for (int t = tid; t < N_NODES; t += 256) hist[t] = 0;
        __syncthreads();
        int b = bid - 512;
        int per = (E + NB_DG - 1) / NB_DG;           // 4096
        int base = b * per;
        for (int kk = tid; kk < per; kk += 256) {
            int k = base + kk;
            if (k >= E) break;
            if (!flags[k]) continue;
            int a = edge_index[k];
            int c = edge_index[E + k];
            a = min(max(a, 0), N_NODES - 1);
            c = min(max(c, 0), N_NODES - 1);
            atomicAdd(&hist[a], 1);
            atomicAdd(&hist[c], 1);
        }
        __syncthreads();
        int* dst = deg_part + (size_t)b * N_NODES;
        for (int t = tid; t < N_NODES; t += 256) dst[t] = hist[t];
    }
}

// =============== K_D: finalize x2/out/z4 (32 blocks) ========================
__global__ __launch_bounds__(256) void kD_finalize(
        const float* __restrict__ x1, const float4* __restrict__ rep_part,
        const int* __restrict__ deg_part,
        float* __restrict__ out_x, float4* __restrict__ z4) {
    int row = blockIdx.x * 256 + threadIdx.x;        // 8192 rows
    float S = 0.f, ax = 0.f, ay = 0.f, az = 0.f;
    #pragma unroll 8
    for (int c = 0; c < 32; ++c) {
        float4 q = rep_part[(size_t)c * N_NODES + row];
        ax += q.x; ay += q.y; az += q.z; S += q.w;
    }
    int d = 0;
    #pragma unroll 8
    for (int q = 0; q < NB_DG; ++q) d += deg_part[(size_t)q * N_NODES + row];
    float xi = x1[3 * row], yi = x1[3 * row + 1], zi = x1[3 * row + 2];
    float ox = xi + xi * S - ax;
    float oy = yi + yi * S - ay;
    float oz = zi + zi * S - az;
    out_x[3 * row] = ox; out_x[3 * row + 1] = oy; out_x[3 * row + 2] = oz;
    float dv = (d == 0) ? 0.0f : 1.0f / sqrtf((float)d + EPS_C);
    z4[row] = make_float4(dv * ox, dv * oy, dv * oz, dv);
}

// =============== K_E: laplacian LDS-hist (64 blocks x 512) ==================
__global__ __launch_bounds__(512) void kE_lap_hist(
        const int* __restrict__ edge_index, const unsigned char* __restrict__ flags,
        const float4* __restrict__ z4, float* __restrict__ lap_part, int E) {
    __shared__ __align__(16) float acc[N3];          // 96 KiB
    int bid = blockIdx.x, tid = threadIdx.x;
    for (int t = tid; t < N3; t += 512) acc[t] = 0.f;
    __syncthreads();
    int per = (E + NB_LP - 1) / NB_LP;               // 4096
    int base = bid * per;
    for (int kk = tid; kk < per; kk += 512) {
        int k = base + kk;
        if (k >= E) break;
        if (!flags[k]) continue;
        int a = edge_index[k];
        int c = edge_index[E + k];
        a = min(max(a, 0), N_NODES - 1);
        c = min(max(c, 0), N_NODES - 1);
        float4 zc = z4[c];
        float4 za = z4[a];
        atomicAdd(&acc[3 * a],     zc.x);
        atomicAdd(&acc[3 * a + 1], zc.y);
        atomicAdd(&acc[3 * a + 2], zc.z);
        atomicAdd(&acc[3 * c],     za.x);
        atomicAdd(&acc[3 * c + 1], za.y);
        atomicAdd(&acc[3 * c + 2], za.z);
    }
    __syncthreads();
    float* dst = lap_part + (size_t)bid * N3;
    for (int t = tid; t < N3; t += 512) dst[t] = acc[t];
}

// =============== K_F: curvature (32 blocks) =================================
__global__ __launch_bounds__(256) void kF_curvature(
        const float* __restrict__ out_x, const float4* __restrict__ z4,
        const float* __restrict__ lap_part, float* __restrict__ out_curv) {
    int row = blockIdx.x * 256 + threadIdx.x;
    float lx = 0.f, ly = 0.f, lz = 0.f;
    #pragma unroll 8
    for (int q = 0; q < NB_LP; ++q) {
        const float* src = lap_part + (size_t)q * N3 + 3 * row;
        lx += src[0]; ly += src[1]; lz += src[2];
    }
    float dv = z4[row].w;
    float Lx = out_x[3 * row]     - dv * lx;
    float Ly = out_x[3 * row + 1] - dv * ly;
    float Lz = out_x[3 * row + 2] - dv * lz;
    out_curv[row] = sqrtf(Lx * Lx + Ly * Ly + Lz * Lz + 1e-12f);
}

extern "C" void kernel_launch(void* const* d_in, const int* in_sizes, int n_in,
                              void* d_out, int out_size, void* d_ws, size_t ws_size,
                              hipStream_t stream) {
    const float* positions   = (const float*)d_in[0];
    const int*   edge_index  = (const int*)d_in[1];
    const int*   dist_idx    = (const int*)d_in[2];
    const float* dist_target = (const float*)d_in[3];
    const float* min_dist    = (const float*)d_in[4];
    float* out = (float*)d_out;

    const int E = in_sizes[1] / 2;   // 262144
    const int K = in_sizes[2] / 2;   // 65536

    // ---- workspace layout (16B aligned), lifetime overlays ----
    // persistent: x1, z4, flags
    // R1 (6 MiB): corr_part (kA->kB), then rep_part 32*8192 f4 (kC->kD)
    // R2 (6 MiB): hash 4MiB (kA->kB) + deg_part 2MiB (kC->kD), then lap_part (kE->kF)
    char* ws = (char*)d_ws;
    const size_t X1_OFF   = 0;                                   //  96 KiB
    const size_t Z4_OFF   = X1_OFF + (size_t)N3 * 4;             // 128 KiB
    const size_t FLAG_OFF = Z4_OFF + (size_t)N_NODES * 16;       // 256 KiB
    const size_t R1_OFF   = FLAG_OFF + (size_t)E;                //   6 MiB
    const size_t R2_OFF   = R1_OFF + (size_t)NB_SC * N3 * 4;     //   6 MiB

    float* x1            = (float*)(ws + X1_OFF);
    float4* z4           = (float4*)(ws + Z4_OFF);
    unsigned char* flags = (unsigned char*)(ws + FLAG_OFF);
    float* corr_part     = (float*)(ws + R1_OFF);
    float4* rep_part     = (float4*)(ws + R1_OFF);               // overlay
    unsigned int* hash   = (unsigned int*)(ws + R2_OFF);
    int* deg_part        = (int*)(ws + R2_OFF + (size_t)HASH_SLOTS * 4);
    float* lap_part      = (float*)(ws + R2_OFF);                // overlay

    kA_corr_hashclear<<<NB_SC + 256, 512, 0, stream>>>(
        positions, dist_idx, dist_target, corr_part, (uint4*)hash, K);

    kB_x1_hashflags<<<96 + (E + 255) / 256, 256, 0, stream>>>(
        positions, corr_part, x1, edge_index, hash, flags, E);

    kC_rep_deg<<<512 + NB_DG, 256, 0, stream>>>(
        x1, min_dist, rep_part, edge_index, flags, deg_part, E);

    kD_finalize<<<32, 256, 0, stream>>>(x1, rep_part, deg_part, out, z4);

    kE_lap_hist<<<NB_LP, 512, 0, stream>>>(edge_index, flags, z4, lap_part, E);

    kF_curvature<<<32, 256, 0, stream>>>(out, z4, lap_part, out + N3);
}